// Round 1
// baseline (852.077 us; speedup 1.0000x reference)
//
#include <hip/hip_runtime.h>
#include <stdint.h>

// Problem constants (fixed by reference): B=8, C=4, H=W=1024, PATCH=16, DOWN=4
// L = 4096 (64x64 patches), L2 = 256 (16x16 patches of the 256x256 pooled map)
#define BDIM    256
#define L_TOTAL 4096
#define L_CHUNK 128

// ---------------------------------------------------------------------------
// K1: per pooled pixel (b, y, x) in [8,256,256], count classes in its 4x4
// block of target, store u8 counts into ws in unfold layout [b][c][k][m]
// with k = (y&15)*16 + (x&15), m = (y>>4)*16 + (x>>4).
// Also zeroes d_out (harness poisons it with 0xAA before every launch).
// ---------------------------------------------------------------------------
__global__ __launch_bounds__(BDIM) void count_kernel(
    const int* __restrict__ tgt, uint8_t* __restrict__ cnt8,
    float* __restrict__ dout) {
  int id = blockIdx.x * BDIM + threadIdx.x;   // 0 .. 524287
  if (id == 0) *dout = 0.f;
  int b = id >> 16;
  int y = (id >> 8) & 255;
  int x = id & 255;
  // pack 4 class counts as 4 u8 fields in one u32 (max 16 each, no overflow)
  uint32_t pc = 0;
  const int* base = tgt + ((size_t)b << 20) + ((size_t)(y << 2) << 10) + (x << 2);
#pragma unroll
  for (int dy = 0; dy < 4; ++dy) {
    int4 v = *(const int4*)(base + (dy << 10));   // 16B coalesced
    pc += (1u << (v.x << 3)) + (1u << (v.y << 3)) +
          (1u << (v.z << 3)) + (1u << (v.w << 3));
  }
  int k = ((y & 15) << 4) | (x & 15);
  int m = ((y >> 4) << 4) | (x >> 4);
  size_t o = ((size_t)b << 18) | ((size_t)k << 8) | (size_t)m;  // [b][c=0][k][m]
#pragma unroll
  for (int c = 0; c < 4; ++c) {
    cnt8[o + ((size_t)c << 16)] = (uint8_t)((pc >> (c << 3)) & 0xFFu);
  }
}

// ---------------------------------------------------------------------------
// K2: block = (l-chunk, m-half, b*4+c). Stages class-c count half-plane
// [256 k][128 m] u8 (32 KB) in LDS. Per l: ballot-compacts the list of k's
// whose target pixel has class c (avg 64/256), integer-accumulates
// att_gt*4096 per m, fuses squared error vs attentions, block-reduces,
// one atomicAdd to d_out.
// ---------------------------------------------------------------------------
__global__ __launch_bounds__(BDIM) void main_kernel(
    const int* __restrict__ tgt, const float* __restrict__ att,
    const uint8_t* __restrict__ cnt8, float* __restrict__ dout) {
  __shared__ uint8_t  cntL[256 * 128];
  __shared__ uint16_t list[256];
  __shared__ uint32_t wcnt[4];
  __shared__ uint32_t tmpAcc[128];
  __shared__ float    wsum[4];

  const int t    = threadIdx.x;
  const int bc   = blockIdx.z;        // 0..31 : b = bc>>2, c = bc&3
  const int b    = bc >> 2;
  const int c    = bc & 3;
  const int half = blockIdx.y;        // 0..1 : which 128 of the 256 m's
  const int l0   = blockIdx.x * L_CHUNK;

  // --- stage counts: cnt8[bc][k][half*128 + mb] -> cntL[k*128 + mb] ---
  {
    const uint32_t* src = (const uint32_t*)(cnt8 + ((size_t)bc << 16));
    uint32_t* dst = (uint32_t*)cntL;
#pragma unroll
    for (int i = 0; i < 32; ++i) {
      int idx = i * 256 + t;          // u32 index, 0..8191
      int k = idx >> 5, col = idx & 31;
      dst[idx] = src[(k << 6) + (half << 5) + col];
    }
  }
  __syncthreads();

  const int lane = t & 63;
  const int wv   = t >> 6;
  const int g    = t >> 7;            // 0: waves 0-1 (m work), 1: waves 2-3
  const int ml   = t & 127;
  float lsum = 0.f;

  for (int il = 0; il < L_CHUNK; ++il) {
    const int l  = l0 + il;
    const int pi = l >> 6, pj = l & 63;

    // --- phase A: load this patch's 256 target pixels (t == k), compact ---
    int h  = (pi << 4) + (t >> 4);
    int w  = (pj << 4) + (t & 15);
    int cv = tgt[((size_t)b << 20) + ((size_t)h << 10) + (size_t)w];
    bool flag = (cv == c);
    unsigned long long mask = __ballot(flag);
    if (lane == 0) wcnt[wv] = (uint32_t)__popcll(mask);
    __syncthreads();
    int rank = (int)__popcll(mask & ((1ull << lane) - 1ull));
    int off = 0;
#pragma unroll
    for (int w2 = 0; w2 < 4; ++w2) off += (w2 < wv) ? (int)wcnt[w2] : 0;
    int ntot = (int)(wcnt[0] + wcnt[1] + wcnt[2] + wcnt[3]);
    if (flag) list[off + rank] = (uint16_t)t;
    __syncthreads();

    // --- phase B: acc[m] = sum over matching k of cnt[k][m] (split j-range
    //     between thread-halves; both halves cover the same 128 m's) ---
    int nt2 = ntot >> 1;
    int jb = g ? nt2 : 0;
    int je = g ? ntot : nt2;
    uint32_t acc = 0;
    for (int j = jb; j < je; ++j) {
      int kk = (int)list[j];                 // LDS broadcast
      acc += (uint32_t)cntL[(kk << 7) + ml]; // 64 consecutive bytes / wave
    }
    if (g) tmpAcc[ml] = acc;
    __syncthreads();

    // --- phase C: fused squared-error (threads g==0 only) ---
    if (!g) {
      uint32_t tot = acc + tmpAcc[ml];
      float agt = (float)tot * (1.f / 4096.f);          // exact
      float av  = att[(((size_t)bc * 4096 + (size_t)l) << 8) + (half << 7) + ml];
      float d   = av - agt;
      lsum += d * d;
    }
    // no trailing barrier needed: next iteration's writes to wcnt happen
    // before a barrier that phase-C readers must also reach; list/tmpAcc
    // writes are gated behind barriers that require all waves.
  }

  // --- block reduction -> one atomic per block ---
#pragma unroll
  for (int o = 32; o > 0; o >>= 1) lsum += __shfl_down(lsum, o, 64);
  if (lane == 0) wsum[wv] = lsum;
  __syncthreads();
  if (t == 0) {
    float s = (wsum[0] + wsum[1]) + (wsum[2] + wsum[3]);
    atomicAdd(dout, s * (1.f / 33554432.f));   // / (B*C*L*L2), exact pow2
  }
}

extern "C" void kernel_launch(void* const* d_in, const int* in_sizes, int n_in,
                              void* d_out, int out_size, void* d_ws, size_t ws_size,
                              hipStream_t stream) {
  (void)in_sizes; (void)n_in; (void)out_size; (void)ws_size;
  // inputs: 0 = pred (unused by the loss), 1 = target (int32), 2 = attentions
  const int*   tgt = (const int*)d_in[1];
  const float* att = (const float*)d_in[2];
  float* dout      = (float*)d_out;
  uint8_t* cnt8    = (uint8_t*)d_ws;   // 8*4*256*256 = 2 MB

  count_kernel<<<dim3(8 * 256 * 256 / BDIM), BDIM, 0, stream>>>(tgt, cnt8, dout);
  dim3 grid(L_TOTAL / L_CHUNK, 2, 32);  // (32 chunks, 2 m-halves, 32 b*c)
  main_kernel<<<grid, BDIM, 0, stream>>>(tgt, att, cnt8, dout);
}

// Round 3
// 282.680 us; speedup vs baseline: 3.0143x; 3.0143x over previous
//
#include <hip/hip_runtime.h>
#include <stdint.h>

// B=8, C=4, H=W=1024, PATCH=16, DOWN=4 -> L=4096, L2=256, K=256
// att_gt[b,c,l,m]*4096 = sum_k ind[b,c,l,k] * cnt[b,c,k,m]  (exact ints <= 4096)
// Strategy: i8 MFMA GEMM (M=4096,N=256,K=256 per (b,c)) with fused MSE epilogue.

#define BDIM 256

typedef int v4i  __attribute__((ext_vector_type(4)));
typedef int v16i __attribute__((ext_vector_type(16)));

// ---------------------------------------------------------------------------
// K1: cls[b][l][k] u8 class map in unfold layout. Thread = (b, l, ky):
// reads 16 consecutive target pixels (one patch row, 64 B), packs to 16 bytes.
// Also zeroes d_out (harness re-poisons it each launch).
// ---------------------------------------------------------------------------
__global__ __launch_bounds__(BDIM) void cls_kernel(
    const int* __restrict__ tgt, uint8_t* __restrict__ cls,
    float* __restrict__ dout) {
  int id = blockIdx.x * BDIM + threadIdx.x;   // 0 .. 524287
  if (id == 0) *dout = 0.f;
  int b  = id >> 16;
  int l  = (id >> 4) & 4095;
  int ky = id & 15;
  int h  = ((l >> 6) << 4) + ky;
  int w  = (l & 63) << 4;
  const int* p = tgt + ((size_t)b << 20) + ((size_t)h << 10) + w;
  uint32_t o[4];
#pragma unroll
  for (int i = 0; i < 4; ++i) {
    int4 v = *(const int4*)(p + (i << 2));
    o[i] = (uint32_t)v.x | ((uint32_t)v.y << 8) |
           ((uint32_t)v.z << 16) | ((uint32_t)v.w << 24);
  }
  *(uint4*)(cls + ((size_t)b << 20) + ((size_t)l << 8) + (ky << 4)) =
      make_uint4(o[0], o[1], o[2], o[3]);
}

// ---------------------------------------------------------------------------
// K2: cntT[b][c][m][k] u8 counts (transposed so B-fragments are contiguous).
// Thread = pooled pixel (b, Y, X): counts classes in its 4x4 full-res block
// by reading 4 u32 from cls.
// ---------------------------------------------------------------------------
__global__ __launch_bounds__(BDIM) void cnt_kernel(
    const uint8_t* __restrict__ cls, uint8_t* __restrict__ cntT) {
  int id = blockIdx.x * BDIM + threadIdx.x;   // 0 .. 524287
  int b = id >> 16;
  int Y = (id >> 8) & 255;
  int X = id & 255;
  int l = ((Y >> 2) << 6) | (X >> 2);
  const uint8_t* p = cls + ((size_t)b << 20) + ((size_t)l << 8) +
                     ((Y & 3) << 6) + ((X & 3) << 2);
  uint32_t pc = 0;   // 4 packed u8 class counts (max 16 each)
#pragma unroll
  for (int dy = 0; dy < 4; ++dy) {
    uint32_t wv = *(const uint32_t*)(p + (dy << 4));
#pragma unroll
    for (int s = 0; s < 32; s += 8)
      pc += 1u << (((wv >> s) & 3u) << 3);
  }
  int m  = ((Y >> 4) << 4) | (X >> 4);
  int km = ((Y & 15) << 4) | (X & 15);
  size_t o = ((size_t)b << 18) | ((size_t)m << 8) | (size_t)km;
#pragma unroll
  for (int c = 0; c < 4; ++c)
    cntT[o + ((size_t)c << 16)] = (uint8_t)((pc >> (c << 3)) & 0xFFu);
}

// ---------------------------------------------------------------------------
// K3: per (b,c): C[l][m] = sum_k ind[l][k]*cnt[k][m] via mfma_i32_32x32x32_i8,
// fused MSE vs att. Block = 4 waves, each wave owns a 32-l strip x all 256 m.
// No LDS / no barriers in the hot loop. A-frags built once per wave, B-frags
// are contiguous 16-B loads from cntT.
// A-frag layout: row = lane&31, k = (lane>>5)*16 + j (j = byte idx 0..15).
// B-frag layout: col = lane&31, k = (lane>>5)*16 + j.
// C/D layout:    col = lane&31, row = (reg&3) + 8*(reg>>2) + 4*(lane>>5).
// ---------------------------------------------------------------------------
__global__ __launch_bounds__(BDIM) void gemm_kernel(
    const uint8_t* __restrict__ cls, const uint8_t* __restrict__ cntT,
    const float* __restrict__ att, float* __restrict__ dout) {
  __shared__ float wsum[4];
  const int t    = threadIdx.x;
  const int wv   = t >> 6, lane = t & 63;
  const int bc   = blockIdx.y;              // 0..31 : b=bc>>2, c=bc&3
  const int b    = bc >> 2, c = bc & 3;
  const int l0   = (blockIdx.x << 7) + (wv << 5);   // wave's 32-l strip
  const int lrow  = lane & 31;
  const int khalf = lane >> 5;

  // --- build the 8 A fragments (k-steps of 32), kept in VGPRs ---
  // classes are < 4 (2 bits), so byte==c  <=>  both low bits of (byte^c) zero.
  // EXACT per-byte test (the classic (x-0x01..)&~x&0x80.. SWAR has borrow
  // false-positives: byte i==0 && byte i+1==0x01 flags byte i+1 — measured
  // as the round-2 absmax 1.17e-2).
  const uint32_t crep = (uint32_t)c * 0x01010101u;
  v4i afr[8];
  const uint8_t* abase = cls + ((size_t)b << 20) +
                         ((size_t)(l0 + lrow) << 8) + (khalf << 4);
#pragma unroll
  for (int kk = 0; kk < 8; ++kk) {
    uint4 raw = *(const uint4*)(abase + (kk << 5));
    uint32_t r[4] = {raw.x, raw.y, raw.z, raw.w};
    v4i a;
#pragma unroll
    for (int i = 0; i < 4; ++i) {
      uint32_t x = r[i] ^ crep;                        // 0 where byte==c
      uint32_t nz = (x | (x >> 1)) & 0x01010101u;      // 1 where byte!=c
      a[i] = (int)(nz ^ 0x01010101u);                  // 1 where byte==c
    }
    afr[kk] = a;
  }

  const uint8_t* bbase = cntT + ((size_t)bc << 16) + (khalf << 4);
  const float* attbase = att + ((size_t)bc << 20) +
                         ((size_t)(l0 + (khalf << 2)) << 8) + lrow;
  float lsum = 0.f;

#pragma unroll 1
  for (int mc = 0; mc < 8; ++mc) {
    // prefetch this tile's att values first (independent of the MFMAs)
    const float* ap = attbase + (mc << 5);
    float av[16];
#pragma unroll
    for (int reg = 0; reg < 16; ++reg)
      av[reg] = ap[((reg & 3) << 8) + ((reg >> 2) << 11)];

    v16i acc = {0,0,0,0,0,0,0,0,0,0,0,0,0,0,0,0};
    const uint8_t* bb = bbase + ((size_t)((mc << 5) + lrow) << 8);
#pragma unroll
    for (int kk = 0; kk < 8; ++kk) {
      uint4 raw = *(const uint4*)(bb + (kk << 5));
      v4i bfr;
      bfr[0] = (int)raw.x; bfr[1] = (int)raw.y;
      bfr[2] = (int)raw.z; bfr[3] = (int)raw.w;
      acc = __builtin_amdgcn_mfma_i32_32x32x32_i8(afr[kk], bfr, acc, 0, 0, 0);
    }
#pragma unroll
    for (int reg = 0; reg < 16; ++reg) {
      float d = fmaf((float)acc[reg], -1.f / 4096.f, av[reg]);
      lsum = fmaf(d, d, lsum);
    }
  }

  // --- block reduction -> one atomic ---
#pragma unroll
  for (int o = 32; o > 0; o >>= 1) lsum += __shfl_down(lsum, o, 64);
  if (lane == 0) wsum[wv] = lsum;
  __syncthreads();
  if (t == 0) {
    float s = (wsum[0] + wsum[1]) + (wsum[2] + wsum[3]);
    atomicAdd(dout, s * (1.f / 33554432.f));   // / (B*C*L*L2)
  }
}

extern "C" void kernel_launch(void* const* d_in, const int* in_sizes, int n_in,
                              void* d_out, int out_size, void* d_ws, size_t ws_size,
                              hipStream_t stream) {
  (void)in_sizes; (void)n_in; (void)out_size; (void)ws_size;
  const int*   tgt = (const int*)d_in[1];     // target (int32 on device)
  const float* att = (const float*)d_in[2];   // attentions
  float* dout      = (float*)d_out;
  uint8_t* cls     = (uint8_t*)d_ws;                    // 8 MB
  uint8_t* cntT    = (uint8_t*)d_ws + (8u << 20);       // 2 MB

  cls_kernel<<<dim3(524288 / BDIM), BDIM, 0, stream>>>(tgt, cls, dout);
  cnt_kernel<<<dim3(524288 / BDIM), BDIM, 0, stream>>>(cls, cntT);
  gemm_kernel<<<dim3(32, 32), BDIM, 0, stream>>>(cls, cntT, att, dout);
}